// Round 11
// baseline (617.904 us; speedup 1.0000x reference)
//
#include <hip/hip_runtime.h>

#define ROW_F4 192    // 768 floats = 192 float4 per output row
#define NCLS   3255   // lcm(3,7,15,31): rows in one class share ALL table indices

typedef float v4f __attribute__((ext_vector_type(4)));

// DIAGNOSTIC ROUND: CRT pure-store kernel with npasses redundant full-output
// passes (idempotent — every pass writes identical correct data).
// Purpose: (1) t_store = (dur_5x - dur_1x)/4 from dur alone;
//          (2) kernel dispatch time 5*t > 269us forces its counter row into
//              rocprof's top-5 (WRITE_SIZE / occupancy / VALUBusy visible).
// Compiler barrier between passes + runtime npasses prevent dead-store elim.
__global__ __launch_bounds__(256) void smart_embedding_kernel(
    const v4f* __restrict__ price_w,
    const v4f* __restrict__ size_w,
    const v4f* __restrict__ exchange_w,   // each table row = 32 float4
    const v4f* __restrict__ pair_w,
    const v4f* __restrict__ level_w,
    const v4f* __restrict__ time_w,
    v4f* __restrict__ out,
    int rows,
    int npasses)
{
    const int tid  = threadIdx.x;
    const int wave = tid >> 6;
    const int lane = tid & 63;
    const int off  = lane & 31;          // float4 slot within a 128-float segment
    const bool hi  = lane >= 32;

    const int cls = blockIdx.x * 4 + wave;   // residue class mod NCLS
    if (cls >= NCLS) return;

    // One-time per-wave table reads (L1-resident).
    const v4f v0 = hi ? size_w[off] : price_w[off];
    const int m1 = hi ? cls % 7  : cls % 3;
    const int m2 = hi ? cls % 31 : cls % 15;
    const v4f v1 = (hi ? pair_w : exchange_w)[m1 * 32 + off];
    const v4f v2 = (hi ? time_w : level_w  )[m2 * 32 + off];

    v4f* const orow0 = out + (size_t)cls * ROW_F4 + lane;
    const size_t step = (size_t)NCLS * ROW_F4;   // 9.54 MB between owned rows

    for (int p = 0; p < npasses; ++p) {
        v4f* o = orow0;
#pragma unroll 4
        for (int r = cls; r < rows; r += NCLS) {
            o[0]   = v0;
            o[64]  = v1;    // imm offset 1024 B
            o[128] = v2;    // imm offset 2048 B
            o += step;
        }
        asm volatile("" ::: "memory");   // pass boundary: no cross-pass DSE
    }
}

extern "C" void kernel_launch(void* const* d_in, const int* in_sizes, int n_in,
                              void* d_out, int out_size, void* d_ws, size_t ws_size,
                              hipStream_t stream) {
    const v4f* price_w    = (const v4f*)d_in[0];
    const v4f* size_w     = (const v4f*)d_in[1];
    const v4f* exchange_w = (const v4f*)d_in[2];
    const v4f* pair_w     = (const v4f*)d_in[3];
    const v4f* level_w    = (const v4f*)d_in[4];
    const v4f* time_w     = (const v4f*)d_in[5];
    v4f* out = (v4f*)d_out;

    const int rows = out_size / 768;             // = num_features
    const int blocks = (NCLS + 3) / 4;           // 814 blocks x 4 waves covers 3255 classes
    const int npasses = 5;                       // DIAGNOSTIC: 5 idempotent passes

    smart_embedding_kernel<<<blocks, 256, 0, stream>>>(
        price_w, size_w, exchange_w, pair_w, level_w, time_w, out, rows, npasses);
}

// Round 12
// 404.515 us; speedup vs baseline: 1.5275x; 1.5275x over previous
//
#include <hip/hip_runtime.h>

#define ROW_F4 192    // 768 floats = 192 float4 per output row
#define NCLS   3255   // lcm(3,7,15,31): rows in one class share ALL table indices

typedef float v4f __attribute__((ext_vector_type(4)));

// FINAL: CRT pure-store kernel. Wave w owns residue class w (mod 3255); all
// rows r ≡ w (mod 3255) share the same exchange/pair/level/time table rows,
// so the four table values are loaded ONCE per wave into registers and the
// steady-state loop is pure stores — no loads, no index math.
//
// Measured (round 11, 5-pass slope probe): 6.88 TB/s store BW = 86% of the
// 8 TB/s HBM peak (above the 6.3 TB/s µbench ceiling and the harness fill's
// 6.25 TB/s). Per-pass kernel time ~58 µs; WRITE_SIZE byte-exact (zero
// amplification). dur_us ≈ 407 is ~349 µs fixed harness work (poison fill
// ~260 µs + reset dispatches) + ~58 µs kernel — kernel is at roofline.
//
// Lane layout per row (192 float4 slots): slot = k*64 + lane, k in {0,1,2};
// lane<32 -> segment 2k (price|exchange|level), lane>=32 -> 2k+1
// (size|pair|time). Each store = 64 lanes x 16 B = 1 KB contiguous.
__global__ __launch_bounds__(256) void smart_embedding_kernel(
    const v4f* __restrict__ price_w,
    const v4f* __restrict__ size_w,
    const v4f* __restrict__ exchange_w,   // each table row = 32 float4
    const v4f* __restrict__ pair_w,
    const v4f* __restrict__ level_w,
    const v4f* __restrict__ time_w,
    v4f* __restrict__ out,
    int rows)
{
    const int tid  = threadIdx.x;
    const int wave = tid >> 6;
    const int lane = tid & 63;
    const int off  = lane & 31;          // float4 slot within a 128-float segment
    const bool hi  = lane >= 32;

    const int cls = blockIdx.x * 4 + wave;   // residue class mod NCLS
    if (cls >= NCLS) return;

    // One-time per-wave table reads (L1-resident).
    const v4f v0 = hi ? size_w[off] : price_w[off];
    const int m1 = hi ? cls % 7  : cls % 3;    // 3|3255, 7|3255
    const int m2 = hi ? cls % 31 : cls % 15;   // 15|3255, 31|3255
    const v4f v1 = (hi ? pair_w : exchange_w)[m1 * 32 + off];
    const v4f v2 = (hi ? time_w : level_w  )[m2 * 32 + off];

    v4f* orow = out + (size_t)cls * ROW_F4 + lane;
    const size_t step = (size_t)NCLS * ROW_F4;   // 9.54 MB between owned rows

    // ~40 iterations; 3 independent coalesced 1 KB stores each, zero loads.
#pragma unroll 4
    for (int r = cls; r < rows; r += NCLS) {
        orow[0]   = v0;
        orow[64]  = v1;    // imm offset 1024 B
        orow[128] = v2;    // imm offset 2048 B
        orow += step;
    }
}

extern "C" void kernel_launch(void* const* d_in, const int* in_sizes, int n_in,
                              void* d_out, int out_size, void* d_ws, size_t ws_size,
                              hipStream_t stream) {
    const v4f* price_w    = (const v4f*)d_in[0];
    const v4f* size_w     = (const v4f*)d_in[1];
    const v4f* exchange_w = (const v4f*)d_in[2];
    const v4f* pair_w     = (const v4f*)d_in[3];
    const v4f* level_w    = (const v4f*)d_in[4];
    const v4f* time_w     = (const v4f*)d_in[5];
    v4f* out = (v4f*)d_out;

    const int rows = out_size / 768;             // = num_features
    const int blocks = (NCLS + 3) / 4;           // 814 blocks x 4 waves covers 3255 classes

    smart_embedding_kernel<<<blocks, 256, 0, stream>>>(
        price_w, size_w, exchange_w, pair_w, level_w, time_w, out, rows);
}